// Round 9
// baseline (95.881 us; speedup 1.0000x reference)
//
#include <hip/hip_runtime.h>
#include <math.h>

#define BB 32
#define HH 256
#define WW 256
#define HW (HH*WW)
#define K_BG 0.1f
#define RELAX 5.0f
#define EPS_D 1e-7
#define RPB 8                          // rows per k_mega BLOCK (amortization unit)
#define RPT 4                          // rows per THREAD (512-thread blocks)
#define MEGA_BLOCKS (BB * (HH / RPB))  // 1024 blocks x 512 thr = 2048 thr/CU (full)
#define GP 8                           // gS guard pad (columns each side)

typedef unsigned long long u64;

// fast sigmoid: 1/(1+2^(-x*log2e)); v_exp_f32+v_rcp_f32, |err|~1e-6 << 1.8e-2 thr
__device__ __forceinline__ float sigf(float x) {
    float e = __builtin_amdgcn_exp2f(-1.44269504f * x);
    return __builtin_amdgcn_rcpf(1.0f + e);
}

__device__ __forceinline__ u64 shflx64(u64 x, int s) {
    return (u64)__shfl_xor((unsigned long long)x, s, 64);
}

// ---------------- binary 5x5 dilation as bit-ops -> row masks ----------------
// R0/R5-proven structure: 512 blocks x 256 threads (16-row bands).
__global__ void k_maskdil(const float* __restrict__ tg, u64* __restrict__ dmaskT,
                          u64* __restrict__ nzmask, unsigned* __restrict__ cnt) {
    __shared__ u64 nz[20][4];
    __shared__ u64 hd[20][4];
    int blk = blockIdx.x;              // 32 images x 16 bands of 16 rows
    int b = blk >> 4, band = blk & 15;
    int r0 = band * 16;
    int t = threadIdx.x, w = t >> 6;
    const float* img = tg + b * HW;
    if (blk == 0 && t == 0) cnt[0] = 0;      // mega ticket reset (consumer launches later)
    float v[20];
    #pragma unroll
    for (int rr = 0; rr < 20; ++rr) {
        int rg = r0 + rr - 2;
        v[rr] = (rg >= 0 && rg < HH) ? img[rg * WW + t] : 0.0f;
    }
    #pragma unroll
    for (int rr = 0; rr < 20; ++rr) {
        u64 bal = __ballot(v[rr] != 0.0f);
        if ((t & 63) == 0) nz[rr][w] = bal;
    }
    __syncthreads();
    if (t < 80) {                      // 20 rows x 4 words: horizontal +-2 dilate
        int rr = t >> 2, k = t & 3;
        u64 m = nz[rr][k];
        u64 ml = (k > 0) ? nz[rr][k - 1] : 0ULL;
        u64 mr = (k < 3) ? nz[rr][k + 1] : 0ULL;
        hd[rr][k] = m | (m << 1) | (m << 2) | (m >> 1) | (m >> 2)
                  | (ml >> 62) | (ml >> 63) | (mr << 62) | (mr << 63);
    }
    if (t < 64) {                      // raw masks for the 16 owned rows
        int rr = t >> 2, k = t & 3;
        nzmask[b * 1024 + (r0 + rr) * 4 + k] = nz[rr + 2][k];
    }
    __syncthreads();
    if (t < 64) {                      // 16 rows x 4 words: vertical +-2 dilate
        int rr = t >> 2, k = t & 3;
        u64 o = hd[rr][k] | hd[rr + 1][k] | hd[rr + 2][k] | hd[rr + 3][k] | hd[rr + 4][k];
        dmaskT[b * 1024 + k * 256 + (r0 + rr)] = o;   // word-major
    }
}

// ---------------- trans: 64x64 bit-tile transpose, ONCE per image -------------
// R9: the butterfly was ~260 instr/thread in mega and recomputed 32x per image.
// 512 tiles (b,g,w) over 128 blocks x 4 waves = 1 tile/wave. Same proven
// butterfly; colmask layout identical to R2's verified k_mega input.
__global__ __launch_bounds__(256) void k_trans(const u64* __restrict__ dmaskT,
                                               u64* __restrict__ colmask) {
    int blk = blockIdx.x;              // b*4 + g
    int b = blk >> 2, g = blk & 3;
    int tid = threadIdx.x;
    int lane = tid & 63, w = tid >> 6;
    const u64 L32 = 0x00000000FFFFFFFFULL, L16 = 0x0000FFFF0000FFFFULL,
              L8  = 0x00FF00FF00FF00FFULL, L4  = 0x0F0F0F0F0F0F0F0FULL,
              L2  = 0x3333333333333333ULL, L1  = 0x5555555555555555ULL;
    u64 x = dmaskT[b * 1024 + w * 256 + g * 64 + lane];   // row (64g+lane), word w
    u64 pp;
    pp = shflx64(x, 32); x = (lane & 32) ? ((x & ~L32) | ((pp & ~L32) >> 32)) : ((x & L32) | ((pp & L32) << 32));
    pp = shflx64(x, 16); x = (lane & 16) ? ((x & ~L16) | ((pp & ~L16) >> 16)) : ((x & L16) | ((pp & L16) << 16));
    pp = shflx64(x,  8); x = (lane &  8) ? ((x & ~L8 ) | ((pp & ~L8 ) >>  8)) : ((x & L8 ) | ((pp & L8 ) <<  8));
    pp = shflx64(x,  4); x = (lane &  4) ? ((x & ~L4 ) | ((pp & ~L4 ) >>  4)) : ((x & L4 ) | ((pp & L4 ) <<  4));
    pp = shflx64(x,  2); x = (lane &  2) ? ((x & ~L2 ) | ((pp & ~L2 ) >>  2)) : ((x & L2 ) | ((pp & L2 ) <<  2));
    pp = shflx64(x,  1); x = (lane &  1) ? ((x & ~L1 ) | ((pp & ~L1 ) >>  1)) : ((x & L1 ) | ((pp & L1 ) <<  1));
    colmask[b * 1024 + g * 256 + w * 64 + lane] = x;      // column (64w+lane), rowgroup g
}

// ---------------- mega: funnel EDT + walk + dice + fused tail -----------------
// R9: no butterfly (k_trans), no colT LDS, one fewer barrier. Vertical distance
// via funnel shifts: dnbits/upbits = +-63-row zero-neighborhood of row i; exact
// unless BOTH empty (needs >=64-tall fat run, p~0.22^64) -> whole-wave rare
// fallback to the old 4-word scan. fg = bit0 of dnbits (free).
__global__ __launch_bounds__(512, 8) void k_mega(const float* __restrict__ preds,
                                                 const u64* __restrict__ colmask,
                                                 const u64* __restrict__ nzmask,
                                                 float4* __restrict__ part1,
                                                 float4* __restrict__ part2,
                                                 unsigned* __restrict__ cnt,
                                                 float* __restrict__ out) {
    __shared__ float gS[RPB][WW + 2 * GP];
    __shared__ float red[8][8];
    __shared__ unsigned stick;
    __shared__ float sI[BB], sC[BB], sA[BB];
    int blk = blockIdx.x;              // b*32 + q ; rows 8q..8q+7
    int b = blk >> 5, q = blk & 31;
    int i0 = q * RPB;
    int tid = threadIdx.x;
    int lane = tid & 63, wv = tid >> 6;      // 8 waves
    int j = tid & 255;                 // this thread's column
    int r0t = (tid >> 8) * RPT;        // row-half: 0 or 4

    float p[RPT];                      // issue all HBM loads first
    #pragma unroll
    for (int rr = 0; rr < RPT; ++rr)
        p[rr] = preds[(b * HH + i0 + r0t + rr) * WW + j];
    int wj = j >> 6;                   // word index of this column
    u64 nzw[RPT];
    #pragma unroll
    for (int rr = 0; rr < RPT; ++rr)
        nzw[rr] = nzmask[b * 1024 + (i0 + r0t + rr) * 4 + wj];
    u64 yw[4];                         // set bit = zero pixel, column j
    #pragma unroll
    for (int g = 0; g < 4; ++g)
        yw[g] = ~colmask[b * 1024 + g * 256 + j];

    if (tid < 128) {                   // gS guard columns: [0..7] and [264..271]
        int rr = tid >> 4, c = tid & 15;
        gS[rr][(c < 8) ? c : (c + 256)] = 1e4f;
    }

    // ---- vertical distance via funnels (exact within +-63; rare fallback) ----
    int g0v[RPT], fgv[RPT], needw[RPT];
    #pragma unroll
    for (int rr = 0; rr < RPT; ++rr) {
        int i = i0 + r0t + rr;
        int iw = i >> 6, ib = i & 63;
        u64 cur = yw[iw];
        u64 nxt = (iw < 3) ? yw[iw + 1] : 0ULL;
        u64 prv = (iw > 0) ? yw[iw - 1] : 0ULL;
        // dnbits bit k = zero-mask of row i+k ; upbits bit (63-k) = row i-k
        u64 dnbits = (cur >> ib) | ((nxt << 1) << (63 - ib));   // two-shift: safe at ib=0
        u64 upbits = (cur << (63 - ib)) | ((prv >> 1) >> ib);   // safe at ib=63
        int fg = (int)(1ULL & ~dnbits);
        fgv[rr] = fg;
        int dn = dnbits ? (__ffsll((unsigned long long)dnbits) - 1) : 10000;
        int up = upbits ? __clzll((long long)upbits) : 10000;
        int g0 = min(dn, up);
        u64 needfull = __ballot(dnbits == 0ULL && upbits == 0ULL);
        if (needfull) {                // essentially never (needs >=64-tall fat run)
            if (dnbits == 0ULL && upbits == 0ULL) {
                u64 lowm  = (2ULL << ib) - 1ULL;
                u64 highm = ~((1ULL << ib) - 1ULL);
                int pu = -1, pd = -1;
                #pragma unroll
                for (int w = 0; w < 4; ++w) {
                    u64 m = (w < iw) ? ~0ULL : ((w == iw) ? lowm : 0ULL);
                    u64 z = yw[w] & m;
                    int cand = (w << 6) + 63 - __clzll(z);
                    pu = z ? cand : pu;
                }
                #pragma unroll
                for (int w = 3; w >= 0; --w) {
                    u64 m = (w > iw) ? ~0ULL : ((w == iw) ? highm : 0ULL);
                    u64 z = yw[w] & m;
                    int cand = (w << 6) + (__ffsll((unsigned long long)z) - 1);
                    pd = z ? cand : pd;
                }
                int upf = (pu >= 0) ? (i - pu) : 10000;
                int dnf = (pd >= 0) ? (pd - i) : 10000;
                g0 = min(min(upf, dnf), 10000);
            }
        }
        u64 anyf = __ballot(fg != 0);  // wave-row fat occupancy (walk skip)
        needw[rr] = (anyf != 0ULL);
        g0v[rr] = g0;
        gS[r0t + rr][GP + j] = (float)g0;
    }
    __syncthreads();

    // ---- min-plus walk: prefix r<=4 (guard-padded) + rare exact tail ----
    float vals[8];
    #pragma unroll
    for (int qq = 0; qq < 6; ++qq) vals[qq] = 0.0f;
    vals[6] = 1e30f; vals[7] = 0.0f;
    #pragma unroll
    for (int rr = 0; rr < RPT; ++rr) {
        int rt = r0t + rr;
        const float* gr = &gS[rt][GP + j];
        float gv = (float)g0v[rr];
        float best = gv * gv;
        if (needw[rr]) {
            #pragma unroll
            for (int r = 1; r <= 4; ++r) {        // branchless prefix, no cndmask
                float rf = (float)(r * r);
                float vl = gr[-r], vr = gr[r];
                best = fminf(best, fminf(fmaf(vl, vl, rf), fmaf(vr, vr, rf)));
            }
            for (int rc = 5; rc < WW + 8; rc += 8) {  // exact tail, 1 test/chunk
                if ((float)(rc * rc) >= best) break;  // valid: best has all r<rc
                #pragma unroll
                for (int dr = 0; dr < 8; ++dr) {
                    int r = rc + dr;
                    float rf = (float)(r * r);
                    int jl = j - r, jr = j + r;
                    float vl = (jl >= 0) ? gr[-r] : 1e4f;
                    float vr = (jr < WW) ? gr[r] : 1e4f;
                    best = fminf(best, fminf(fmaf(vl, vl, rf), fmaf(vr, vr, rf)));
                }
            }
        }
        float dv = __builtin_amdgcn_sqrtf(best);
        float sp = sigf(p[rr]);
        float sd = sigf(dv * (1.0f / RELAX));
        float tv = (float)((nzw[rr] >> (j & 63)) & 1ULL);
        vals[0] += sp * sd * tv;                  // A
        vals[1] += sp * tv;                       // B
        vals[2] += sp * sd;                       // A'
        vals[3] += sp;                            // B'
        vals[4] += fgv[rr] ? 0.0f : sp;           // C' = sp*(1-fat)
        vals[5] += tv;                            // T
        vals[6] = fminf(vals[6], dv);
        vals[7] = fmaxf(vals[7], dv);
    }
    for (int off = 32; off > 0; off >>= 1) {
        #pragma unroll
        for (int qq = 0; qq < 6; ++qq) vals[qq] += __shfl_down(vals[qq], off, 64);
        vals[6] = fminf(vals[6], __shfl_down(vals[6], off, 64));
        vals[7] = fmaxf(vals[7], __shfl_down(vals[7], off, 64));
    }
    if (lane == 0) {
        #pragma unroll
        for (int qq = 0; qq < 8; ++qq) red[qq][wv] = vals[qq];
    }
    __syncthreads();
    if (tid == 0) {
        float s[8];
        #pragma unroll
        for (int qq = 0; qq < 6; ++qq) {
            s[qq] = 0.0f;
            #pragma unroll
            for (int k = 0; k < 8; ++k) s[qq] += red[qq][k];
        }
        s[6] = red[6][0]; s[7] = red[7][0];
        #pragma unroll
        for (int k = 1; k < 8; ++k) {
            s[6] = fminf(s[6], red[6][k]);
            s[7] = fmaxf(s[7], red[7][k]);
        }
        part1[blk] = make_float4(s[0], s[1], s[2], s[3]);
        part2[blk] = make_float4(s[4], s[5], s[6], s[7]);
        __threadfence();                          // release partials
        stick = atomicAdd(&cnt[0], 1u);
    }
    __syncthreads();
    if (stick != MEGA_BLOCKS - 1) return;

    // ---- fused tail: last block folds 32 partials/image (proven pattern) ----
    __threadfence();                              // acquire partials
    #pragma unroll
    for (int pass = 0; pass < 2; ++pass) {
        int img = pass * 16 + (tid >> 5);         // 16 images per pass, 32 lanes each
        int k = tid & 31;
        float4 p1 = part1[img * 32 + k];
        float4 p2 = part2[img * 32 + k];
        float v2[8] = {p1.x, p1.y, p1.z, p1.w, p2.x, p2.y, p2.z, p2.w};
        for (int off = 16; off > 0; off >>= 1) {
            #pragma unroll
            for (int qq = 0; qq < 6; ++qq) v2[qq] += __shfl_down(v2[qq], off, 32);
            v2[6] = fminf(v2[6], __shfl_down(v2[6], off, 32));
            v2[7] = fmaxf(v2[7], __shfl_down(v2[7], off, 32));
        }
        if (k == 0) {
            float A = v2[0], Bs = v2[1], Ap = v2[2], Bp = v2[3];
            float Cp = v2[4], T = v2[5], dmn = v2[6], dmx = v2[7];
            float inter, card, any;
            if (T > 0.0f) {            // has_fg == (sum targets > 0), as reference
                float smin = sigf(dmn * (1.0f / RELAX));
                float smax = sigf(dmx * (1.0f / RELAX));
                float m = smax - smin;
                float denom = (m > 0.0f) ? m : 1.0f;
                inter = (A - smin * Bs) / denom;   // Σ sp·t·(1-fat) == 0 exactly
                card  = (Ap - smin * Bp) / denom + K_BG * Cp + T;
                any = 1.0f;
            } else {                   // dm = 1 - t ; t == 0 everywhere
                inter = 0.0f;
                card = Bp - Bs + T;
                any = 0.0f;
            }
            sI[img] = inter; sC[img] = card; sA[img] = any;
        }
    }
    __syncthreads();
    if (tid == 0) {
        double I = 0.0, C = 0.0;
        int any = 0;
        for (int bb = 0; bb < BB; ++bb) {
            I += (double)sI[bb]; C += (double)sC[bb];
            any |= (sA[bb] > 0.0f);
        }
        double dice = 2.0 * I / fmax(C, (double)EPS_D);
        out[0] = any ? (float)(1.0 - dice) : 0.0f;
    }
}

extern "C" void kernel_launch(void* const* d_in, const int* in_sizes, int n_in,
                              void* d_out, int out_size, void* d_ws, size_t ws_size,
                              hipStream_t stream) {
    const float* preds = (const float*)d_in[0];
    const float* tg    = (const float*)d_in[1];
    float* out = (float*)d_out;

    u64* dmaskT   = (u64*)d_ws;                      // 256 KB
    u64* nzmask   = dmaskT + BB * 1024;              // 256 KB
    u64* colmask  = nzmask + BB * 1024;              // 256 KB
    float4* part1 = (float4*)(colmask + BB * 1024);  // 16 KB, 16B-aligned
    float4* part2 = part1 + MEGA_BLOCKS;             // 16 KB
    unsigned* cnt = (unsigned*)(part2 + MEGA_BLOCKS);

    hipLaunchKernelGGL(k_maskdil, dim3(BB * 16), dim3(WW), 0, stream,
                       tg, dmaskT, nzmask, cnt);
    hipLaunchKernelGGL(k_trans, dim3(BB * 4), dim3(256), 0, stream,
                       dmaskT, colmask);
    hipLaunchKernelGGL(k_mega, dim3(MEGA_BLOCKS), dim3(512), 0, stream,
                       preds, colmask, nzmask, part1, part2, cnt, out);
}